// Round 4
// baseline (948.343 us; speedup 1.0000x reference)
//
#include <hip/hip_runtime.h>
#include <math.h>

#define N 256

// xor-swizzle within 32-lane half (DS pipe, 1 instr)
template<int XM>
__device__ __forceinline__ float swz(float v) {
  int i = __builtin_amdgcn_ds_swizzle(__builtin_bit_cast(int, v), (XM << 10) | 0x1F);
  return __builtin_bit_cast(float, i);
}
// DPP lane-shuffle (VALU pipe, not DS)
template<int CTRL>
__device__ __forceinline__ float dppmv(float v) {
  int y = __builtin_amdgcn_update_dpp(0, __builtin_bit_cast(int, v), CTRL, 0xF, 0xF, true);
  return __builtin_bit_cast(float, y);
}
// sum over 32-lane half: 4 VALU rotate-adds + 1 swizzle; all lanes get the sum
__device__ __forceinline__ float red32s(float v) {
  v += dppmv<0x121>(v);   // row_ror:1
  v += dppmv<0x122>(v);   // row_ror:2
  v += dppmv<0x124>(v);   // row_ror:4
  v += dppmv<0x128>(v);   // row_ror:8  -> 16-lane row sum, all lanes
  v += swz<16>(v);        // cross the two 16-rows of the 32-half
  return v;
}

__global__ __launch_bounds__(1024, 4) void icvp_kernel(
    const float* __restrict__ X, const float* __restrict__ A,
    const float* __restrict__ Bv, float* __restrict__ out)
{
  const int p     = blockIdx.x;
  const int t     = threadIdx.x;
  const int w     = t >> 6;
  const int lane  = t & 63;
  const int h     = lane >> 5;
  const int j     = lane & 31;       // col-block within group
  const int G     = w * 2 + h;       // row-group: owns rows G*8..+8
  const int c_red = t >> 2;          // reducer: column owned (x4 dup over h4)
  const int h4    = t & 3;
  const int chnk  = c_red >> 3;
  const int coff  = c_red & 7;

  __shared__ __align__(16) float part[32 * 256];   // [group][xor-swizzled col]
  __shared__ __align__(16) float xn[N], x0n[N], gn[N];
  __shared__ float wsc[16], wsc2[16], scal[4];
  __shared__ int vflag[2];

  // ---- A tile: rows G*8..+8, cols j*8..+8 (64 fp32 in regs) ----
  float Areg[8][8];
  {
    const float* Ap = A + (size_t)p * (N * N) + (G * 8) * N + j * 8;
    #pragma unroll
    for (int r = 0; r < 8; ++r) {
      const float4* src = reinterpret_cast<const float4*>(Ap + r * N);
      float4 a0 = src[0], a1 = src[1];
      Areg[r][0]=a0.x; Areg[r][1]=a0.y; Areg[r][2]=a0.z; Areg[r][3]=a0.w;
      Areg[r][4]=a1.x; Areg[r][5]=a1.y; Areg[r][6]=a1.z; Areg[r][7]=a1.w;
    }
  }
  if (t < N) { float xv = X[p * N + t]; xn[t] = xv; x0n[t] = xv; }
  if (t < 2) vflag[t] = 0;

  // ---- row norms (DPP reduce), scale A, b_tight in regs ----
  float btl[8];
  {
    const float4* bp = reinterpret_cast<const float4*>(Bv + p * N + G * 8);
    float4 b0 = bp[0], b1 = bp[1];
    float bl[8] = {b0.x,b0.y,b0.z,b0.w,b1.x,b1.y,b1.z,b1.w};
    #pragma unroll
    for (int r = 0; r < 8; ++r) {
      float s = 0.f;
      #pragma unroll
      for (int c = 0; c < 8; ++c) s = fmaf(Areg[r][c], Areg[r][c], s);
      s = red32s(s);
      float inv = 1.0f / fmaxf(sqrtf(s), 1e-12f);
      #pragma unroll
      for (int c = 0; c < 8; ++c) Areg[r][c] *= inv;
      btl[r] = bl[r] * inv - 1e-3f;     // b_w - MU_INSIDE
    }
  }

  // ---- helpers ----
  auto fwd8 = [&](const float (&vv)[8], float (&s)[8]) {  // s[r] = full (A vv)[G*8+r]
    #pragma unroll
    for (int r = 0; r < 8; ++r) {
      float a = 0.f;
      #pragma unroll
      for (int c = 0; c < 8; ++c) a = fmaf(Areg[r][c], vv[c], a);
      s[r] = a;
    }
    #pragma unroll
    for (int r = 0; r < 8; ++r) s[r] = red32s(s[r]);
  };
  auto trans_write = [&](const float (&rr)[8]) {  // in-lane A^T partial, xor-swizzled b128 store
    float gp0[8];
    #pragma unroll
    for (int c = 0; c < 8; ++c) {
      float a = 0.f;
      #pragma unroll
      for (int r2 = 0; r2 < 8; ++r2) a = fmaf(Areg[r2][c], rr[r2], a);
      gp0[c] = a;
    }
    float4* dst = reinterpret_cast<float4*>(&part[(G << 8) + (((j ^ G) & 31) << 3)]);
    dst[0] = make_float4(gp0[0], gp0[1], gp0[2], gp0[3]);
    dst[1] = make_float4(gp0[4], gp0[5], gp0[6], gp0[7]);
  };
  auto zero_write = [&]() {
    float4* dst = reinterpret_cast<float4*>(&part[(G << 8) + (((j ^ G) & 31) << 3)]);
    dst[0] = make_float4(0.f, 0.f, 0.f, 0.f);
    dst[1] = make_float4(0.f, 0.f, 0.f, 0.f);
  };
  auto col_reduce = [&]() {  // 8 b32 reads (2-way banks) + 2 quad_perm folds
    float g = 0.f;
    #pragma unroll
    for (int i = 0; i < 8; ++i) {
      const int grp = h4 + 4 * i;
      g += part[(grp << 8) + (((chnk ^ grp) & 31) << 3) + coff];
    }
    g += dppmv<0xB1>(g);   // fold lane^1 (quad_perm [1,0,3,2])
    g += dppmv<0x4E>(g);   // fold lane^2 (quad_perm [2,3,0,1])
    return g;              // full A^T-vec at column c_red (x4 dup, bitwise identical)
  };
  auto load8v = [&](const float* base, float (&d)[8]) {   // 2 b128 reads
    const float4* v4 = reinterpret_cast<const float4*>(base + j * 8);
    float4 a0 = v4[0], a1 = v4[1];
    d[0]=a0.x; d[1]=a0.y; d[2]=a0.z; d[3]=a0.w; d[4]=a1.x; d[5]=a1.y; d[6]=a1.z; d[7]=a1.w;
  };

  // ---- power iteration (5 iters) ----
  float vloc[8];
  #pragma unroll
  for (int c = 0; c < 8; ++c) vloc[c] = 0.0625f;   // ones/||ones|| exact

  for (int pit = 0; pit < 5; ++pit) {
    float av[8];
    fwd8(vloc, av);
    trans_write(av);
    __syncthreads();
    float g = col_reduce();                 // AtAv[c_red]
    if (h4 == 0) gn[c_red] = g;
    float ss = (h4 == 0) ? g * g : 0.f;
    ss = red32s(ss); ss += __shfl_xor(ss, 32);
    if (lane == 0) wsc[w] = ss;
    __syncthreads();
    if (t == 0) {
      float s = 0.f;
      #pragma unroll
      for (int i = 0; i < 16; ++i) s += wsc[i];
      scal[0] = sqrtf(s) + 1e-12f;
    }
    __syncthreads();
    load8v(gn, vloc);
    {
      float den = scal[0];
      #pragma unroll
      for (int c = 0; c < 8; ++c) vloc[c] /= den;
    }
  }
  // eta = 1/(sum((A v)^2) + rho)
  {
    float av[8];
    fwd8(vloc, av);
    float ss = 0.f;
    #pragma unroll
    for (int r = 0; r < 8; ++r) ss = fmaf(av[r], av[r], ss);  // group-uniform
    ss += __shfl_xor(ss, 32);
    if (lane == 0) wsc[w] = ss;
    __syncthreads();
    if (t == 0) {
      float s = 0.f;
      #pragma unroll
      for (int i = 0; i < 16; ++i) s += wsc[i];
      scal[1] = 1.0f / (s + 1e-12f);
    }
    __syncthreads();
  }
  const float eta = scal[1];

  // ---- UVP: up to 30 iterations, 2 barriers each; exact early exit ----
  // Once relu(Ax - b_tight) == 0 for ALL rows, g = 0 exactly and x is a
  // bitwise fixed point: all remaining reference iterations are the identity.
  float xloc[8];
  load8v(xn, xloc);
  float xred = xn[c_red];
  for (int k = 0; k < 30; ++k) {
    float s[8];
    fwd8(xloc, s);
    float rl[8];
    float m = 0.f;
    #pragma unroll
    for (int r = 0; r < 8; ++r) { rl[r] = fmaxf(s[r] - btl[r], 0.f); m = fmaxf(m, rl[r]); }
    m = fmaxf(m, __shfl_xor(m, 32));        // wave-uniform max violation
    const bool wviol = (m > 0.f);
    if (wviol) {
      if (lane == 0) vflag[k & 1] = 1;
      trans_write(rl);
    } else {
      zero_write();                          // exact: feasible wave contributes 0
    }
    __syncthreads();
    const int act = vflag[k & 1];
    if (act) {
      float g = col_reduce();
      xred = fmaf(-eta, g, xred);
      if (h4 == 0) xn[c_red] = xred;
    }
    if (t == 0) vflag[(k + 1) & 1] = 0;
    __syncthreads();
    if (!act) break;                         // whole problem feasible: fixed point
    load8v(xn, xloc);
  }

  // ---- stage 2: gate + alpha ----
  float x0loc[8], dloc[8];
  load8v(x0n, x0loc);
  #pragma unroll
  for (int c = 0; c < 8; ++c) dloc[c] = x0loc[c] - xloc[c];
  float sx[8], sd[8];
  fwd8(xloc, sx);
  fwd8(dloc, sd);
  float mv = -INFINITY, aim = INFINITY;
  #pragma unroll
  for (int r = 0; r < 8; ++r) {
    float bw = btl[r] + 1e-3f;
    float ax = sx[r], ad = sd[r];
    mv = fmaxf(mv, ax - bw);
    float ai = (ad > 0.f) ? (bw - ax) / (ad + 1e-12f) : INFINITY;
    aim = fminf(aim, ai);
  }
  // mv/aim are group-uniform; fold across the wave's two groups
  mv  = fmaxf(mv,  __shfl_xor(mv, 32));
  aim = fminf(aim, __shfl_xor(aim, 32));
  if (lane == 0) { wsc[w] = mv; wsc2[w] = aim; }
  __syncthreads();
  if (t == 0) {
    float M = -INFINITY, Al = INFINITY;
    #pragma unroll
    for (int i = 0; i < 16; ++i) { M = fmaxf(M, wsc[i]); Al = fminf(Al, wsc2[i]); }
    if (!isfinite(Al)) Al = 1.0f;
    Al = fminf(fmaxf(Al - 1e-6f, 0.f), 1.0f);
    scal[2] = M; scal[3] = Al;
  }
  __syncthreads();
  if (t < N) {
    float xv = xn[t];
    float d  = x0n[t] - xv;
    out[p * N + t] = (scal[2] <= 1e-7f) ? fmaf(scal[3], d, xv) : xv;
  }
}

extern "C" void kernel_launch(void* const* d_in, const int* in_sizes, int n_in,
                              void* d_out, int out_size, void* d_ws, size_t ws_size,
                              hipStream_t stream) {
  const float* X  = (const float*)d_in[0];
  const float* A  = (const float*)d_in[1];
  const float* Bv = (const float*)d_in[2];
  float* out = (float*)d_out;
  const int nprob = in_sizes[0] / N;   // 512
  icvp_kernel<<<nprob, 1024, 0, stream>>>(X, A, Bv, out);
}

// Round 5
// 293.308 us; speedup vs baseline: 3.2333x; 3.2333x over previous
//
#include <hip/hip_runtime.h>
#include <math.h>

#define N 256

// xor-swizzle within 32-lane half (DS pipe, 1 instr)
template<int XM>
__device__ __forceinline__ float swz(float v) {
  int i = __builtin_amdgcn_ds_swizzle(__builtin_bit_cast(int, v), (XM << 10) | 0x1F);
  return __builtin_bit_cast(float, i);
}
// DPP lane-shuffle (VALU pipe, not DS)
template<int CTRL>
__device__ __forceinline__ float dppmv(float v) {
  int y = __builtin_amdgcn_update_dpp(0, __builtin_bit_cast(int, v), CTRL, 0xF, 0xF, true);
  return __builtin_bit_cast(float, y);
}
// sum over 32-lane half: 4 VALU rotate-adds + 1 swizzle; all lanes get the sum
__device__ __forceinline__ float red32s(float v) {
  v += dppmv<0x121>(v);   // row_ror:1
  v += dppmv<0x122>(v);   // row_ror:2
  v += dppmv<0x124>(v);   // row_ror:4
  v += dppmv<0x128>(v);   // row_ror:8  -> 16-lane row sum, all lanes
  v += swz<16>(v);        // cross the two 16-rows of the 32-half
  return v;
}

__global__ __launch_bounds__(1024, 4) void icvp_kernel(
    const float* __restrict__ X, const float* __restrict__ A,
    const float* __restrict__ Bv, float* __restrict__ out)
{
  const int p     = blockIdx.x;
  const int t     = threadIdx.x;
  const int w     = t >> 6;
  const int lane  = t & 63;
  const int h     = lane >> 5;
  const int j     = lane & 31;       // col-block within group
  const int G     = w * 2 + h;       // row-group: owns rows G*8..+8
  const int c_red = t >> 2;          // reducer: column owned (x4 dup over h4)
  const int h4    = t & 3;
  const int chnk  = c_red >> 3;
  const int coff  = c_red & 7;

  __shared__ __align__(16) float part[32 * 256];   // [group][xor-swizzled col]
  __shared__ __align__(16) float xn[N], x0n[N], gn[N];
  __shared__ __align__(16) float wsc[16];
  __shared__ __align__(16) float wsc2[16];
  __shared__ float scal[4];
  __shared__ int iflag;

  // ---- A tile: rows G*8..+8, cols j*8..+8 (64 fp32 in regs) ----
  float Areg[8][8];
  {
    const float* Ap = A + (size_t)p * (N * N) + (G * 8) * N + j * 8;
    #pragma unroll
    for (int r = 0; r < 8; ++r) {
      const float4* src = reinterpret_cast<const float4*>(Ap + r * N);
      float4 a0 = src[0], a1 = src[1];
      Areg[r][0]=a0.x; Areg[r][1]=a0.y; Areg[r][2]=a0.z; Areg[r][3]=a0.w;
      Areg[r][4]=a1.x; Areg[r][5]=a1.y; Areg[r][6]=a1.z; Areg[r][7]=a1.w;
    }
  }
  if (t < N) { float xv = X[p * N + t]; xn[t] = xv; x0n[t] = xv; }

  // ---- row norms (DPP reduce), scale A, b_tight in regs ----
  float btl[8];
  {
    const float4* bp = reinterpret_cast<const float4*>(Bv + p * N + G * 8);
    float4 b0 = bp[0], b1 = bp[1];
    float bl[8] = {b0.x,b0.y,b0.z,b0.w,b1.x,b1.y,b1.z,b1.w};
    #pragma unroll
    for (int r = 0; r < 8; ++r) {
      float s = 0.f;
      #pragma unroll
      for (int c = 0; c < 8; ++c) s = fmaf(Areg[r][c], Areg[r][c], s);
      s = red32s(s);
      float inv = 1.0f / fmaxf(sqrtf(s), 1e-12f);
      #pragma unroll
      for (int c = 0; c < 8; ++c) Areg[r][c] *= inv;
      btl[r] = bl[r] * inv - 1e-3f;     // b_w - MU_INSIDE
    }
  }

  // ---- helpers ----
  auto fwd8 = [&](const float (&vv)[8], float (&s)[8]) {  // s[r] = full (A vv)[G*8+r]
    #pragma unroll
    for (int r = 0; r < 8; ++r) {
      float a = 0.f;
      #pragma unroll
      for (int c = 0; c < 8; ++c) a = fmaf(Areg[r][c], vv[c], a);
      s[r] = a;
    }
    #pragma unroll
    for (int r = 0; r < 8; ++r) s[r] = red32s(s[r]);
  };
  auto trans_write = [&](const float (&rr)[8]) {  // in-lane A^T partial, xor-swizzled b128 store
    float gp0[8];
    #pragma unroll
    for (int c = 0; c < 8; ++c) {
      float a = 0.f;
      #pragma unroll
      for (int r2 = 0; r2 < 8; ++r2) a = fmaf(Areg[r2][c], rr[r2], a);
      gp0[c] = a;
    }
    float4* dst = reinterpret_cast<float4*>(&part[(G << 8) + (((j ^ G) & 31) << 3)]);
    dst[0] = make_float4(gp0[0], gp0[1], gp0[2], gp0[3]);
    dst[1] = make_float4(gp0[4], gp0[5], gp0[6], gp0[7]);
  };
  auto col_reduce = [&]() {  // 8 b32 reads (2-way banks) + 2 quad_perm folds
    float g = 0.f;
    #pragma unroll
    for (int i = 0; i < 8; ++i) {
      const int grp = h4 + 4 * i;
      g += part[(grp << 8) + (((chnk ^ grp) & 31) << 3) + coff];
    }
    g += dppmv<0xB1>(g);   // fold lane^1 (quad_perm [1,0,3,2])
    g += dppmv<0x4E>(g);   // fold lane^2 (quad_perm [2,3,0,1])
    return g;              // full A^T-vec at column c_red (x4 dup, bitwise identical)
  };
  auto load8v = [&](const float* base, float (&d)[8]) {   // 2 b128 reads
    const float4* v4 = reinterpret_cast<const float4*>(base + j * 8);
    float4 a0 = v4[0], a1 = v4[1];
    d[0]=a0.x; d[1]=a0.y; d[2]=a0.z; d[3]=a0.w; d[4]=a1.x; d[5]=a1.y; d[6]=a1.z; d[7]=a1.w;
  };

  // ---- power iteration (5 iters) ----
  float vloc[8];
  #pragma unroll
  for (int c = 0; c < 8; ++c) vloc[c] = 0.0625f;   // ones/||ones|| exact

  for (int pit = 0; pit < 5; ++pit) {
    float av[8];
    fwd8(vloc, av);
    trans_write(av);
    __syncthreads();
    float g = col_reduce();                 // AtAv[c_red]
    if (h4 == 0) gn[c_red] = g;
    float ss = (h4 == 0) ? g * g : 0.f;
    ss = red32s(ss); ss += __shfl_xor(ss, 32);
    if (lane == 0) wsc[w] = ss;
    __syncthreads();
    if (t == 0) {
      float s = 0.f;
      #pragma unroll
      for (int i = 0; i < 16; ++i) s += wsc[i];
      scal[0] = sqrtf(s) + 1e-12f;
    }
    __syncthreads();
    load8v(gn, vloc);
    {
      float den = scal[0];
      #pragma unroll
      for (int c = 0; c < 8; ++c) vloc[c] /= den;
    }
  }
  // eta = 1/(sum((A v)^2) + rho)
  {
    float av[8];
    fwd8(vloc, av);
    float ss = 0.f;
    #pragma unroll
    for (int r = 0; r < 8; ++r) ss = fmaf(av[r], av[r], ss);  // group-uniform
    ss += __shfl_xor(ss, 32);
    if (lane == 0) wsc[w] = ss;
    __syncthreads();
    if (t == 0) {
      float s = 0.f;
      #pragma unroll
      for (int i = 0; i < 16; ++i) s += wsc[i];
      scal[1] = 1.0f / (s + 1e-12f);
    }
    __syncthreads();
  }
  const float eta = scal[1];

  // ---- UVP: up to 30 iterations, 2 barriers each; exact early exit ----
  // When relu(Ax - b_tight) == 0 for all rows, partials are +0, g == +0, and
  // xred = fmaf(-eta, 0, xred) is bitwise identity -> remaining reference
  // iterations are identity; exiting early is exact. All Areg uses stay in
  // straight-line code (R4's spill trigger was Areg use under divergence).
  float xloc[8];
  load8v(xn, xloc);
  float xred = xn[c_red];
  int act = 1;
  for (int k = 0; (k < 30) & act; ++k) {
    float s[8];
    fwd8(xloc, s);
    float rl[8];
    float m = 0.f;
    #pragma unroll
    for (int r = 0; r < 8; ++r) { rl[r] = fmaxf(s[r] - btl[r], 0.f); m = fmaxf(m, rl[r]); }
    trans_write(rl);                         // unconditional (zeros when feasible)
    m = fmaxf(m, __shfl_xor(m, 32));
    if (lane == 0) wsc[w] = m;               // per-wave max violation
    __syncthreads();
    float g = col_reduce();
    xred = fmaf(-eta, g, xred);              // identity when g == 0
    if (h4 == 0) xn[c_red] = xred;
    if (t == 0) {
      float M = 0.f;
      #pragma unroll
      for (int i = 0; i < 16; ++i) M = fmaxf(M, wsc[i]);
      iflag = (M > 0.f) ? 1 : 0;
    }
    __syncthreads();
    act = iflag;                             // block-uniform
    load8v(xn, xloc);
  }

  // ---- stage 2: gate + alpha ----
  float x0loc[8], dloc[8];
  load8v(x0n, x0loc);
  #pragma unroll
  for (int c = 0; c < 8; ++c) dloc[c] = x0loc[c] - xloc[c];
  float sx[8], sd[8];
  fwd8(xloc, sx);
  fwd8(dloc, sd);
  float mv = -INFINITY, aim = INFINITY;
  #pragma unroll
  for (int r = 0; r < 8; ++r) {
    float bw = btl[r] + 1e-3f;
    float ax = sx[r], ad = sd[r];
    mv = fmaxf(mv, ax - bw);
    float ai = (ad > 0.f) ? (bw - ax) / (ad + 1e-12f) : INFINITY;
    aim = fminf(aim, ai);
  }
  // mv/aim are group-uniform; fold across the wave's two groups
  mv  = fmaxf(mv,  __shfl_xor(mv, 32));
  aim = fminf(aim, __shfl_xor(aim, 32));
  if (lane == 0) { wsc[w] = mv; wsc2[w] = aim; }
  __syncthreads();
  if (t == 0) {
    float M = -INFINITY, Al = INFINITY;
    #pragma unroll
    for (int i = 0; i < 16; ++i) { M = fmaxf(M, wsc[i]); Al = fminf(Al, wsc2[i]); }
    if (!isfinite(Al)) Al = 1.0f;
    Al = fminf(fmaxf(Al - 1e-6f, 0.f), 1.0f);
    scal[2] = M; scal[3] = Al;
  }
  __syncthreads();
  if (t < N) {
    float xv = xn[t];
    float d  = x0n[t] - xv;
    out[p * N + t] = (scal[2] <= 1e-7f) ? fmaf(scal[3], d, xv) : xv;
  }
}

extern "C" void kernel_launch(void* const* d_in, const int* in_sizes, int n_in,
                              void* d_out, int out_size, void* d_ws, size_t ws_size,
                              hipStream_t stream) {
  const float* X  = (const float*)d_in[0];
  const float* A  = (const float*)d_in[1];
  const float* Bv = (const float*)d_in[2];
  float* out = (float*)d_out;
  const int nprob = in_sizes[0] / N;   // 512
  icvp_kernel<<<nprob, 1024, 0, stream>>>(X, A, Bv, out);
}

// Round 6
// 286.802 us; speedup vs baseline: 3.3066x; 1.0227x over previous
//
#include <hip/hip_runtime.h>
#include <math.h>

#define N 256

// xor-swizzle within 32-lane half (DS pipe, 1 instr)
template<int XM>
__device__ __forceinline__ float swz(float v) {
  int i = __builtin_amdgcn_ds_swizzle(__builtin_bit_cast(int, v), (XM << 10) | 0x1F);
  return __builtin_bit_cast(float, i);
}
// DPP lane-shuffle (VALU pipe, not DS)
template<int CTRL>
__device__ __forceinline__ float dppmv(float v) {
  int y = __builtin_amdgcn_update_dpp(0, __builtin_bit_cast(int, v), CTRL, 0xF, 0xF, true);
  return __builtin_bit_cast(float, y);
}
// sum over 32-lane half: 4 VALU rotate-adds + 1 swizzle; all lanes get the sum
__device__ __forceinline__ float red32s(float v) {
  v += dppmv<0x121>(v);   // row_ror:1
  v += dppmv<0x122>(v);   // row_ror:2
  v += dppmv<0x124>(v);   // row_ror:4
  v += dppmv<0x128>(v);   // row_ror:8  -> 16-lane row sum, all lanes
  v += swz<16>(v);        // cross the two 16-rows of the 32-half
  return v;
}

__global__ __launch_bounds__(1024, 4) void icvp_kernel(
    const float* __restrict__ X, const float* __restrict__ A,
    const float* __restrict__ Bv, float* __restrict__ out)
{
  const int p     = blockIdx.x;
  const int t     = threadIdx.x;
  const int w     = t >> 6;
  const int lane  = t & 63;
  const int h     = lane >> 5;
  const int j     = lane & 31;       // col-block within group
  const int G     = w * 2 + h;       // row-group: owns rows G*8..+8
  const int c_red = t >> 2;          // reducer: column owned (x4 dup over h4)
  const int h4    = t & 3;
  const int chnk  = c_red >> 3;
  const int coff  = c_red & 7;

  __shared__ __align__(16) float part[32 * 256];   // [group][xor-swizzled col]
  __shared__ __align__(16) float xn[N], x0n[N], gn[N];
  __shared__ __align__(16) float wsc[16];
  __shared__ __align__(16) float wsc2[16];
  __shared__ float scal[4];

  // ---- A tile: rows G*8..+8, cols j*8..+8 (64 fp32 in regs) ----
  float Areg[8][8];
  {
    const float* Ap = A + (size_t)p * (N * N) + (G * 8) * N + j * 8;
    #pragma unroll
    for (int r = 0; r < 8; ++r) {
      const float4* src = reinterpret_cast<const float4*>(Ap + r * N);
      float4 a0 = src[0], a1 = src[1];
      Areg[r][0]=a0.x; Areg[r][1]=a0.y; Areg[r][2]=a0.z; Areg[r][3]=a0.w;
      Areg[r][4]=a1.x; Areg[r][5]=a1.y; Areg[r][6]=a1.z; Areg[r][7]=a1.w;
    }
  }
  if (t < N) { float xv = X[p * N + t]; xn[t] = xv; x0n[t] = xv; }

  // ---- row norms (DPP reduce), scale A; store btl32 = -(b_w - mu)/32 ----
  float btl32[8];
  {
    const float4* bp = reinterpret_cast<const float4*>(Bv + p * N + G * 8);
    float4 b0 = bp[0], b1 = bp[1];
    float bl[8] = {b0.x,b0.y,b0.z,b0.w,b1.x,b1.y,b1.z,b1.w};
    #pragma unroll
    for (int r = 0; r < 8; ++r) {
      float s = 0.f;
      #pragma unroll
      for (int c = 0; c < 8; ++c) s = fmaf(Areg[r][c], Areg[r][c], s);
      s = red32s(s);
      float inv = 1.0f / fmaxf(sqrtf(s), 1e-12f);
      #pragma unroll
      for (int c = 0; c < 8; ++c) Areg[r][c] *= inv;
      btl32[r] = (bl[r] * inv - 1e-3f) * -0.03125f;  // -(b_w - MU)/32, exact scale
    }
  }

  // ---- helpers ----
  auto fwd8 = [&](const float (&vv)[8], float (&s)[8]) {  // s[r] = full (A vv)[G*8+r]
    #pragma unroll
    for (int r = 0; r < 8; ++r) {
      float a = 0.f;
      #pragma unroll
      for (int c = 0; c < 8; ++c) a = fmaf(Areg[r][c], vv[c], a);
      s[r] = a;
    }
    #pragma unroll
    for (int r = 0; r < 8; ++r) s[r] = red32s(s[r]);
  };
  // fused: s[r] = (A vv)[row] - b_tight[row]  (b_tight pre-scaled into the init)
  auto fwd8_bt = [&](const float (&vv)[8], float (&s)[8]) {
    #pragma unroll
    for (int r = 0; r < 8; ++r) {
      float a = btl32[r];
      #pragma unroll
      for (int c = 0; c < 8; ++c) a = fmaf(Areg[r][c], vv[c], a);
      s[r] = a;
    }
    #pragma unroll
    for (int r = 0; r < 8; ++r) s[r] = red32s(s[r]);
  };
  auto trans_write = [&](const float (&rr)[8]) {  // in-lane A^T partial, xor-swizzled b128 store
    float gp0[8];
    #pragma unroll
    for (int c = 0; c < 8; ++c) {
      float a = 0.f;
      #pragma unroll
      for (int r2 = 0; r2 < 8; ++r2) a = fmaf(Areg[r2][c], rr[r2], a);
      gp0[c] = a;
    }
    float4* dst = reinterpret_cast<float4*>(&part[(G << 8) + (((j ^ G) & 31) << 3)]);
    dst[0] = make_float4(gp0[0], gp0[1], gp0[2], gp0[3]);
    dst[1] = make_float4(gp0[4], gp0[5], gp0[6], gp0[7]);
  };
  auto col_reduce = [&]() {  // 8 b32 reads (2-way banks) + 2 quad_perm folds
    float g = 0.f;
    #pragma unroll
    for (int i = 0; i < 8; ++i) {
      const int grp = h4 + 4 * i;
      g += part[(grp << 8) + (((chnk ^ grp) & 31) << 3) + coff];
    }
    g += dppmv<0xB1>(g);   // fold lane^1 (quad_perm [1,0,3,2])
    g += dppmv<0x4E>(g);   // fold lane^2 (quad_perm [2,3,0,1])
    return g;              // full A^T-vec at column c_red (x4 dup, bitwise identical)
  };
  auto load8v = [&](const float* base, float (&d)[8]) {   // 2 b128 reads
    const float4* v4 = reinterpret_cast<const float4*>(base + j * 8);
    float4 a0 = v4[0], a1 = v4[1];
    d[0]=a0.x; d[1]=a0.y; d[2]=a0.z; d[3]=a0.w; d[4]=a1.x; d[5]=a1.y; d[6]=a1.z; d[7]=a1.w;
  };

  // ---- power iteration (5 iters) ----
  float vloc[8];
  #pragma unroll
  for (int c = 0; c < 8; ++c) vloc[c] = 0.0625f;   // ones/||ones|| exact

  for (int pit = 0; pit < 5; ++pit) {
    float av[8];
    fwd8(vloc, av);
    trans_write(av);
    __syncthreads();
    float g = col_reduce();                 // AtAv[c_red]
    if (h4 == 0) gn[c_red] = g;
    float ss = (h4 == 0) ? g * g : 0.f;
    ss = red32s(ss); ss += __shfl_xor(ss, 32);
    if (lane == 0) wsc[w] = ss;
    __syncthreads();
    if (t == 0) {
      float s = 0.f;
      #pragma unroll
      for (int i = 0; i < 16; ++i) s += wsc[i];
      scal[0] = sqrtf(s) + 1e-12f;
    }
    __syncthreads();
    load8v(gn, vloc);
    {
      float den = scal[0];
      #pragma unroll
      for (int c = 0; c < 8; ++c) vloc[c] /= den;
    }
  }
  // eta = 1/(sum((A v)^2) + rho)
  {
    float av[8];
    fwd8(vloc, av);
    float ss = 0.f;
    #pragma unroll
    for (int r = 0; r < 8; ++r) ss = fmaf(av[r], av[r], ss);  // group-uniform
    ss += __shfl_xor(ss, 32);
    if (lane == 0) wsc[w] = ss;
    __syncthreads();
    if (t == 0) {
      float s = 0.f;
      #pragma unroll
      for (int i = 0; i < 16; ++i) s += wsc[i];
      scal[1] = 1.0f / (s + 1e-12f);
    }
    __syncthreads();
  }
  const float eta = scal[1];

  // ---- UVP: 30 iterations, 2 barriers each, lean body ----
  float xloc[8];
  load8v(xn, xloc);
  float xred = xn[c_red];
  #pragma unroll 1
  for (int k = 0; k < 30; ++k) {
    float s[8];
    fwd8_bt(xloc, s);                        // s = Ax - b_tight (fused)
    float rl[8];
    #pragma unroll
    for (int r = 0; r < 8; ++r) rl[r] = fmaxf(s[r], 0.f);
    trans_write(rl);
    __syncthreads();
    float g = col_reduce();
    xred = fmaf(-eta, g, xred);
    if (h4 == 0) xn[c_red] = xred;
    __syncthreads();
    load8v(xn, xloc);
  }

  // ---- stage 2: gate + alpha ----
  float x0loc[8], dloc[8];
  load8v(x0n, x0loc);
  #pragma unroll
  for (int c = 0; c < 8; ++c) dloc[c] = x0loc[c] - xloc[c];
  float sx[8], sd[8];
  fwd8(xloc, sx);
  fwd8(dloc, sd);
  float mv = -INFINITY, aim = INFINITY;
  #pragma unroll
  for (int r = 0; r < 8; ++r) {
    float bw = fmaf(-32.f, btl32[r], 1e-3f);  // recover b_w exactly
    float ax = sx[r], ad = sd[r];
    mv = fmaxf(mv, ax - bw);
    float ai = (ad > 0.f) ? (bw - ax) / (ad + 1e-12f) : INFINITY;
    aim = fminf(aim, ai);
  }
  // mv/aim are group-uniform; fold across the wave's two groups
  mv  = fmaxf(mv,  __shfl_xor(mv, 32));
  aim = fminf(aim, __shfl_xor(aim, 32));
  if (lane == 0) { wsc[w] = mv; wsc2[w] = aim; }
  __syncthreads();
  if (t == 0) {
    float M = -INFINITY, Al = INFINITY;
    #pragma unroll
    for (int i = 0; i < 16; ++i) { M = fmaxf(M, wsc[i]); Al = fminf(Al, wsc2[i]); }
    if (!isfinite(Al)) Al = 1.0f;
    Al = fminf(fmaxf(Al - 1e-6f, 0.f), 1.0f);
    scal[2] = M; scal[3] = Al;
  }
  __syncthreads();
  if (t < N) {
    float xv = xn[t];
    float d  = x0n[t] - xv;
    out[p * N + t] = (scal[2] <= 1e-7f) ? fmaf(scal[3], d, xv) : xv;
  }
}

extern "C" void kernel_launch(void* const* d_in, const int* in_sizes, int n_in,
                              void* d_out, int out_size, void* d_ws, size_t ws_size,
                              hipStream_t stream) {
  const float* X  = (const float*)d_in[0];
  const float* A  = (const float*)d_in[1];
  const float* Bv = (const float*)d_in[2];
  float* out = (float*)d_out;
  const int nprob = in_sizes[0] / N;   // 512
  icvp_kernel<<<nprob, 1024, 0, stream>>>(X, A, Bv, out);
}